// Round 1
// baseline (194.509 us; speedup 1.0000x reference)
//
#include <hip/hip_runtime.h>

// Classwise circular-buffer queue update.
// occ_i = rank of proposal i within its class (original index order).
// slot  = (tail[l] + occ) % Q.  Proposal is the final writer of its slot
// iff occ >= k_l - Q (the last min(k,Q) ranks cover distinct slots).
// => conflict-free scatter of proposal index into idx[C*Q], then one
// gather pass building the output.

#define HBLK 1024  // proposals per histogram block

__global__ void k_hist(const int* __restrict__ lab, int* __restrict__ cnt,
                       int N, int C) {
    int b = blockIdx.x;
    int i = b * HBLK + threadIdx.x;
    if (i < N) {
        int l = lab[i];
        if (l >= 0 && l < C) atomicAdd(&cnt[(size_t)b * C + l], 1);
    }
}

__global__ void k_prefix(int* __restrict__ cnt, int* __restrict__ ktot,
                         int C, int NB) {
    int l = blockIdx.x * blockDim.x + threadIdx.x;
    if (l >= C) return;
    int run = 0;
    for (int b = 0; b < NB; ++b) {
        int t = cnt[(size_t)b * C + l];
        cnt[(size_t)b * C + l] = run;  // exclusive prefix per (block,label)
        run += t;
    }
    ktot[l] = run;  // total count per label
}

__global__ void k_slots(const int* __restrict__ lab, const int* __restrict__ tail,
                        const int* __restrict__ cnt, const int* __restrict__ ktot,
                        int* __restrict__ idx, int N, int C, int Q) {
    __shared__ int slab[HBLK];
    int b = blockIdx.x;
    int t = threadIdx.x;
    int i = b * HBLK + t;
    int l = (i < N) ? lab[i] : -1;
    slab[t] = l;
    __syncthreads();
    if (l < 0 || l >= C) return;
    // local rank within this block (broadcast LDS reads; all lanes read same j)
    int local = 0;
    for (int j = 0; j < t; ++j) local += (slab[j] == l) ? 1 : 0;
    int occ = cnt[(size_t)b * C + l] + local;
    int kk = ktot[l];
    if (occ >= kk - Q) {
        int s = (tail[l] + occ) % Q;
        if (s < 0) s += Q;            // python-style mod (divisor sign)
        idx[l * Q + s] = i;           // unique (class,slot) per qualifier
    }
}

__global__ void k_gather(const float4* __restrict__ feat,
                         const float4* __restrict__ queue,
                         const int* __restrict__ idx,
                         float4* __restrict__ out,
                         long long total4, int F4) {
    long long g = (long long)blockIdx.x * blockDim.x + threadIdx.x;
    if (g >= total4) return;
    int r = (int)(g / F4);
    int c = (int)(g - (long long)r * F4);
    int id = idx[r];  // broadcast within wave (64 lanes = one 256-float row)
    const float4* src = (id >= 0) ? (feat + (size_t)id * F4 + c)
                                  : (queue + (size_t)r * F4 + c);
    out[g] = *src;
}

extern "C" void kernel_launch(void* const* d_in, const int* in_sizes, int n_in,
                              void* d_out, int out_size, void* d_ws, size_t ws_size,
                              hipStream_t stream) {
    const float* feat  = (const float*)d_in[0];
    const float* queue = (const float*)d_in[1];
    const int*   lab   = (const int*)d_in[2];
    const int*   tail  = (const int*)d_in[3];

    const int N = in_sizes[2];
    const int C = in_sizes[3];
    const int F = in_sizes[0] / N;
    const int Q = in_sizes[1] / (C * F);
    const int NB = (N + HBLK - 1) / HBLK;

    int* idx  = (int*)d_ws;                    // C*Q
    int* cnt  = idx + (size_t)C * Q;           // NB*C
    int* ktot = cnt + (size_t)NB * C;          // C

    hipMemsetAsync(idx, 0xFF, (size_t)C * Q * sizeof(int), stream);   // -1
    hipMemsetAsync(cnt, 0x00, (size_t)NB * C * sizeof(int), stream);

    k_hist<<<NB, HBLK, 0, stream>>>(lab, cnt, N, C);
    k_prefix<<<(C + 255) / 256, 256, 0, stream>>>(cnt, ktot, C, NB);
    k_slots<<<NB, HBLK, 0, stream>>>(lab, tail, cnt, ktot, idx, N, C, Q);

    const int F4 = F / 4;
    const long long total4 = (long long)C * Q * F4;
    const int gblocks = (int)((total4 + 255) / 256);
    k_gather<<<gblocks, 256, 0, stream>>>((const float4*)feat,
                                          (const float4*)queue, idx,
                                          (float4*)d_out, total4, F4);
}

// Round 3
// 192.213 us; speedup vs baseline: 1.0119x; 1.0119x over previous
//
#include <hip/hip_runtime.h>

// Classwise circular-buffer queue update.
// occ_i = rank of proposal i within its class (original index order).
// slot  = (tail[l] + occ) % Q.  Proposal i is the FINAL writer of its slot
// iff occ >= k_l - Q (the last min(k,Q) ranks cover distinct slots exactly
// once). => conflict-free scatter of proposal index into idx[C*Q], then one
// streaming gather pass building the output.

typedef float vf4 __attribute__((ext_vector_type(4)));  // native vec for nt builtins

#define HBLK 1024  // proposals per histogram block

// Zero own cnt row, then histogram this block's labels into it.
__global__ void k_hist(const int* __restrict__ lab, int* __restrict__ cnt,
                       int N, int C) {
    int b = blockIdx.x;
    int t = threadIdx.x;
    int* row = cnt + (size_t)b * C;
    for (int j = t; j < C; j += HBLK) row[j] = 0;
    __syncthreads();
    int i = b * HBLK + t;
    if (i < N) {
        int l = lab[i];
        if (l >= 0 && l < C) atomicAdd(&row[l], 1);
    }
}

// Column-wise exclusive prefix over blocks; total per label; init idx = -1.
__global__ void k_prefix(int* __restrict__ cnt, int* __restrict__ ktot,
                         int* __restrict__ idx, int C, int NB, int Q) {
    int l = blockIdx.x * blockDim.x + threadIdx.x;
    if (l >= C) return;
    int run = 0;
    for (int b = 0; b < NB; ++b) {
        int t = cnt[(size_t)b * C + l];
        cnt[(size_t)b * C + l] = run;  // exclusive prefix per (block,label)
        run += t;
    }
    ktot[l] = run;                     // total count per label
    for (int q = 0; q < Q; ++q) idx[l * Q + q] = -1;
}

__global__ void k_slots(const int* __restrict__ lab, const int* __restrict__ tail,
                        const int* __restrict__ cnt, const int* __restrict__ ktot,
                        int* __restrict__ idx, int N, int C, int Q) {
    __shared__ int slab[HBLK];
    int b = blockIdx.x;
    int t = threadIdx.x;
    int i = b * HBLK + t;
    int l = (i < N) ? lab[i] : -1;
    slab[t] = l;
    __syncthreads();
    if (l < 0 || l >= C) return;
    // local rank within this block (broadcast LDS reads; all lanes read same j)
    int local = 0;
    for (int j = 0; j < t; ++j) local += (slab[j] == l) ? 1 : 0;
    int occ = cnt[(size_t)b * C + l] + local;
    int kk = ktot[l];
    if (occ >= kk - Q) {
        int s = (tail[l] + occ) % Q;
        if (s < 0) s += Q;            // python-style mod (positive divisor)
        idx[l * Q + s] = i;           // unique (class,slot) per qualifier
    }
}

// One wave (64 lanes x float4) per 256-float row; grid-stride; nt streaming.
__global__ void k_gather(const vf4* __restrict__ feat,
                         const vf4* __restrict__ queue,
                         const int* __restrict__ idx,
                         vf4* __restrict__ out,
                         long long total4, int F4) {
    long long stride = (long long)gridDim.x * blockDim.x;
    if (F4 == 64) {
        for (long long g = (long long)blockIdx.x * blockDim.x + threadIdx.x;
             g < total4; g += stride) {
            int r = (int)(g >> 6);
            int c = (int)(g & 63);
            int id = idx[r];  // broadcast within wave
            const vf4* src = (id >= 0) ? (feat + ((size_t)id << 6) + c)
                                       : (queue + ((size_t)r << 6) + c);
            vf4 v = __builtin_nontemporal_load(src);
            __builtin_nontemporal_store(v, &out[g]);
        }
    } else {
        for (long long g = (long long)blockIdx.x * blockDim.x + threadIdx.x;
             g < total4; g += stride) {
            int r = (int)(g / F4);
            int c = (int)(g - (long long)r * F4);
            int id = idx[r];
            const vf4* src = (id >= 0) ? (feat + (size_t)id * F4 + c)
                                       : (queue + (size_t)r * F4 + c);
            vf4 v = __builtin_nontemporal_load(src);
            __builtin_nontemporal_store(v, &out[g]);
        }
    }
}

extern "C" void kernel_launch(void* const* d_in, const int* in_sizes, int n_in,
                              void* d_out, int out_size, void* d_ws, size_t ws_size,
                              hipStream_t stream) {
    const float* feat  = (const float*)d_in[0];
    const float* queue = (const float*)d_in[1];
    const int*   lab   = (const int*)d_in[2];
    const int*   tail  = (const int*)d_in[3];

    const int N = in_sizes[2];
    const int C = in_sizes[3];
    const int F = in_sizes[0] / N;
    const int Q = in_sizes[1] / (C * F);
    const int NB = (N + HBLK - 1) / HBLK;

    int* idx  = (int*)d_ws;                    // C*Q
    int* cnt  = idx + (size_t)C * Q;           // NB*C
    int* ktot = cnt + (size_t)NB * C;          // C

    k_hist<<<NB, HBLK, 0, stream>>>(lab, cnt, N, C);
    k_prefix<<<(C + 255) / 256, 256, 0, stream>>>(cnt, ktot, idx, C, NB, Q);
    k_slots<<<NB, HBLK, 0, stream>>>(lab, tail, cnt, ktot, idx, N, C, Q);

    const int F4 = F / 4;
    const long long total4 = (long long)C * Q * F4;
    int gblocks = 2048;
    long long need = (total4 + 255) / 256;
    if (need < gblocks) gblocks = (int)need;
    k_gather<<<gblocks, 256, 0, stream>>>((const vf4*)feat,
                                          (const vf4*)queue, idx,
                                          (vf4*)d_out, total4, F4);
}